// Round 7
// baseline (351.606 us; speedup 1.0000x reference)
//
#include <hip/hip_runtime.h>
#include <hip/hip_bf16.h>
#include <hip/hip_cooperative_groups.h>

namespace cg = cooperative_groups;

#define B_ 4
#define S_ 4096
#define DM 512
#define DH 64

#define NEG_BIG (-3.0e38f)
#define MCLAMP  (-1.0e30f)

typedef __attribute__((ext_vector_type(8))) short short8b;   // 8 bf16 (4 VGPRs)
typedef __attribute__((ext_vector_type(4))) float f32x4;     // MFMA C/D

__device__ __forceinline__ f32x4 MFMA16(short8b a, short8b b, f32x4 c) {
    return __builtin_amdgcn_mfma_f32_16x16x32_bf16(a, b, c, 0, 0, 0);
}

__device__ __forceinline__ float bf2f(unsigned short u) {
    unsigned int x = ((unsigned int)u) << 16;
    float f;
    __builtin_memcpy(&f, &x, 4);
    return f;
}
__device__ __forceinline__ unsigned short f2bf_rne(float f) {
    unsigned int u = __float_as_uint(f);
    u += 0x7FFFu + ((u >> 16) & 1u);
    return (unsigned short)(u >> 16);
}
__device__ __forceinline__ unsigned int pk2(unsigned short a, unsigned short b) {
    return (unsigned int)a | ((unsigned int)b << 16);
}

// async HBM->LDS DMA, 16B/lane.
__device__ __forceinline__ void gload16(const void* gp, void* lp) {
    __builtin_amdgcn_global_load_lds(
        (const __attribute__((address_space(1))) void*)gp,
        (__attribute__((address_space(3))) void*)lp, 16, 0, 0);
}

// ---------------------------------------------------------------------------
// Fused cooperative kernel: detect (block-local) -> proj (hi/lo bf16 MFMA
// GEMM, 3 tiles/block) -> threadfence + grid.sync -> flash (round-6 verified
// algorithm). One dispatch replaces three: rounds 5/6 accounting bounds the
// inter-dispatch overhead at >= 53 us (top-5 cutoff proves proj <= 82 while
// total residual was ~135-165), which this eliminates.
// Grid 256 x 512thr, LDS 137.5KB -> 1 block/CU, exactly co-resident.
// ---------------------------------------------------------------------------
__global__ __launch_bounds__(512, 1) void fused_kernel(
    const void* __restrict__ xq, const void* __restrict__ xk,
    const void* __restrict__ xv,
    const void* __restrict__ Wq, const void* __restrict__ Wk,
    const void* __restrict__ Wv,
    const void* __restrict__ bq, const void* __restrict__ bk,
    const void* __restrict__ bv,
    unsigned short* __restrict__ Qhp, unsigned short* __restrict__ Qlp,
    unsigned short* __restrict__ Khp, unsigned short* __restrict__ Klp,
    unsigned short* __restrict__ Vthp, unsigned short* __restrict__ Vtlp,
    void* __restrict__ out)
{
    const int blk  = blockIdx.x;
    const int t    = threadIdx.x;
    const int lane = t & 63;
    const int w    = t >> 6;
    const int l15  = lane & 15;
    const int l4   = lane >> 4;

    // flash layout: [0,8192) Q/P | [8192,+65536) buf0 | [73728,+65536) buf1
    // proj layout:  [0,32768) Xh/Xl/Wh/Wl | [32768,+16896) f32 C[64][66]
    __shared__ __align__(16) char smem[8192 + 2 * 65536];
    __shared__ float Mg[4][32];
    __shared__ float Lg[4][32];
    __shared__ float Ltot[32];
    __shared__ int sdet;

    // ---- phase 0: block-local dtype detect ----
    if (t == 0) sdet = 0;
    __syncthreads();
    if (t < 256) {
        const unsigned short* u = (const unsigned short*)xq;
        int cnt = 0;
        #pragma unroll
        for (int k = 0; k < 8; ++k) {
            unsigned short x = u[t * 8 + k];
            int e = (x >> 7) & 0xFF;
            if (e >= 135 || (e > 0 && e <= 95)) ++cnt;
        }
        atomicAdd(&sdet, cnt);
    }
    __syncthreads();
    const bool f32 = (sdet > 64);   // 1 -> fp32 inputs/outputs, 0 -> bf16

    // =======================================================================
    // Phase 1: projections (3 sequential 64-row x 64-head tiles per block)
    // =======================================================================
    {
        const int row0 = blk * 64;
        const int m    = t >> 8;          // 0: stage X, 1: stage W
        const int tt   = t & 255;
        const int srow = tt >> 2;         // 0..63
        const int sseg = tt & 3;          // 16-elem segment
        const int swz  = (srow & 7) << 4;
        const int rq   = (w & 3) * 16;    // wave's row block
        const int nb   = (w >> 2) * 2;    // wave's first head tile
        const int arow = rq + l15;

        #pragma unroll 1
        for (int which = 0; which < 3; ++which) {
            const void* x    = (which == 0) ? xq : (which == 1) ? xk : xv;
            const void* W    = (which == 0) ? Wq : (which == 1) ? Wk : Wv;
            const void* bias = (which == 0) ? bq : (which == 1) ? bk : bv;

            f32x4 acc[2];
            acc[0] = f32x4{0.f, 0.f, 0.f, 0.f};
            acc[1] = f32x4{0.f, 0.f, 0.f, 0.f};

            #pragma unroll 1
            for (int kc = 0; kc < DM / 64; ++kc) {
                const int k0 = kc * 64;
                __syncthreads();   // prev chunk frag reads / prev C reads done

                if (f32) {
                    const float* p = (m == 0)
                        ? (const float*)x + (size_t)(row0 + srow) * DM + k0 + sseg * 16
                        : (const float*)W + (size_t)srow * DM + k0 + sseg * 16;
                    float v[16];
                    #pragma unroll
                    for (int j = 0; j < 4; ++j) {
                        float4 f = *reinterpret_cast<const float4*>(p + j * 4);
                        v[j*4+0] = f.x; v[j*4+1] = f.y;
                        v[j*4+2] = f.z; v[j*4+3] = f.w;
                    }
                    unsigned short hh[16], ll[16];
                    #pragma unroll
                    for (int j = 0; j < 16; ++j) {
                        unsigned short hb = f2bf_rne(v[j]);
                        hh[j] = hb;
                        ll[j] = f2bf_rne(v[j] - bf2f(hb));
                    }
                    char* dh = smem + m * 16384 + srow * 128;
                    char* dl = dh + 8192;
                    #pragma unroll
                    for (int g = 0; g < 2; ++g) {
                        const int off = (sseg * 32 + g * 16) ^ swz;
                        uint4 hu, lu;
                        hu.x = pk2(hh[g*8+0], hh[g*8+1]); hu.y = pk2(hh[g*8+2], hh[g*8+3]);
                        hu.z = pk2(hh[g*8+4], hh[g*8+5]); hu.w = pk2(hh[g*8+6], hh[g*8+7]);
                        lu.x = pk2(ll[g*8+0], ll[g*8+1]); lu.y = pk2(ll[g*8+2], ll[g*8+3]);
                        lu.z = pk2(ll[g*8+4], ll[g*8+5]); lu.w = pk2(ll[g*8+6], ll[g*8+7]);
                        *reinterpret_cast<uint4*>(dh + off) = hu;
                        *reinterpret_cast<uint4*>(dl + off) = lu;
                    }
                } else {
                    const unsigned short* p = (m == 0)
                        ? (const unsigned short*)x + (size_t)(row0 + srow) * DM + k0 + sseg * 16
                        : (const unsigned short*)W + (size_t)srow * DM + k0 + sseg * 16;
                    char* dh = smem + m * 16384 + srow * 128;
                    char* dl = dh + 8192;
                    const uint4 z = {0u, 0u, 0u, 0u};
                    #pragma unroll
                    for (int g = 0; g < 2; ++g) {
                        uint4 hv = *reinterpret_cast<const uint4*>(p + g * 8);
                        const int off = (sseg * 32 + g * 16) ^ swz;
                        *reinterpret_cast<uint4*>(dh + off) = hv;
                        *reinterpret_cast<uint4*>(dl + off) = z;   // lo = 0 exact
                    }
                }
                __syncthreads();   // stage visible

                short8b xh[2], xl[2];
                #pragma unroll
                for (int ks = 0; ks < 2; ++ks) {
                    const int off = arow * 128 + ((ks * 64 + l4 * 16) ^ ((arow & 7) << 4));
                    xh[ks] = *reinterpret_cast<const short8b*>(smem + off);
                    xl[ks] = *reinterpret_cast<const short8b*>(smem + 8192 + off);
                }
                #pragma unroll
                for (int n2 = 0; n2 < 2; ++n2) {
                    const int brow = (nb + n2) * 16 + l15;
                    #pragma unroll
                    for (int ks = 0; ks < 2; ++ks) {
                        const int off = brow * 128 + ((ks * 64 + l4 * 16) ^ ((brow & 7) << 4));
                        short8b wh = *reinterpret_cast<const short8b*>(smem + 16384 + off);
                        short8b wl = *reinterpret_cast<const short8b*>(smem + 24576 + off);
                        acc[n2] = MFMA16(xh[ks], wl, acc[n2]);   // xhi * wlo
                        acc[n2] = MFMA16(xl[ks], wh, acc[n2]);   // xlo * whi
                        acc[n2] = MFMA16(xh[ks], wh, acc[n2]);   // xhi * whi
                    }
                }
            }

            // ---- epilogue: acc -> LDS f32 C[64][66] -> planes ----
            __syncthreads();   // last chunk frag reads complete
            float* C = reinterpret_cast<float*>(smem + 32768);
            #pragma unroll
            for (int n2 = 0; n2 < 2; ++n2)
                #pragma unroll
                for (int r = 0; r < 4; ++r)
                    C[(rq + l4 * 4 + r) * 66 + (nb + n2) * 16 + l15] = acc[n2][r];
            __syncthreads();

            if (which < 2) {
                unsigned short* ph = (which == 0) ? Qhp : Khp;
                unsigned short* pl = (which == 0) ? Qlp : Klp;
                const float scale = (which == 0) ? 0.125f : 1.0f;   // 1/sqrt(64)
                const int r_  = t >> 3;          // 0..63
                const int c0_ = (t & 7) * 8;     // 8 heads per thread
                unsigned short hh[8], ll[8];
                #pragma unroll
                for (int j = 0; j < 8; ++j) {
                    const float bv_ = f32 ? ((const float*)bias)[c0_ + j]
                                          : bf2f(((const unsigned short*)bias)[c0_ + j]);
                    const float v = (C[r_ * 66 + c0_ + j] + bv_) * scale;
                    unsigned short hb = f2bf_rne(v);
                    hh[j] = hb;
                    ll[j] = f2bf_rne(v - bf2f(hb));
                }
                const size_t off = (size_t)(row0 + r_) * DH + c0_;
                uint4 hu, lu;
                hu.x = pk2(hh[0], hh[1]); hu.y = pk2(hh[2], hh[3]);
                hu.z = pk2(hh[4], hh[5]); hu.w = pk2(hh[6], hh[7]);
                lu.x = pk2(ll[0], ll[1]); lu.y = pk2(ll[2], ll[3]);
                lu.z = pk2(ll[4], ll[5]); lu.w = pk2(ll[6], ll[7]);
                *reinterpret_cast<uint4*>(ph + off) = hu;
                *reinterpret_cast<uint4*>(pl + off) = lu;
            } else {
                const int c_ = t & 63;           // head (= Vt d-row)
                const int rb = (t >> 6) * 8;     // 8 rows per thread
                const int bb = row0 >> 12;       // batch
                const int s0 = row0 & (S_ - 1);
                const float bv_ = f32 ? ((const float*)bias)[c_]
                                      : bf2f(((const unsigned short*)bias)[c_]);
                unsigned short hh[8], ll[8];
                #pragma unroll
                for (int i = 0; i < 8; ++i) {
                    const float v = C[(rb + i) * 66 + c_] + bv_;
                    unsigned short hb = f2bf_rne(v);
                    hh[i] = hb;
                    ll[i] = f2bf_rne(v - bf2f(hb));
                }
                const size_t off = (size_t)(bb * 64 + c_) * S_ + s0 + rb;
                uint4 hu, lu;
                hu.x = pk2(hh[0], hh[1]); hu.y = pk2(hh[2], hh[3]);
                hu.z = pk2(hh[4], hh[5]); hu.w = pk2(hh[6], hh[7]);
                lu.x = pk2(ll[0], ll[1]); lu.y = pk2(ll[2], ll[3]);
                lu.z = pk2(ll[4], ll[5]); lu.w = pk2(ll[6], ll[7]);
                *reinterpret_cast<uint4*>(Vthp + off) = hu;
                *reinterpret_cast<uint4*>(Vtlp + off) = lu;
            }
        }
    }

    // ---- planes written -> device-scope visibility -> grid barrier ----
    __threadfence();
    cg::this_grid().sync();

    // =======================================================================
    // Phase 2: flash attention (round-6 verified algorithm, unchanged)
    // =======================================================================
    {
        const int pair = blk & 63;
        const int b    = blk >> 6;
        const int qh   = w & 1;
        const int kh   = w >> 1;

        const size_t bS = (size_t)b * S_;
        const bool f32o = f32;

        const int qp   = t >> 8;
        const int qrow = (t & 255) >> 3;
        const int qsg  = t & 7;

        const int klaneoff = ((lane >> 3) << 7) +
                             ((((lane & 7) << 4)) ^ ((lane >> 3) << 4));
        const int vrl = lane >> 4;
        const int voff0 = (vrl << 13) + ((((lane & 15) << 4)) ^ (vrl << 4));
        const int voff1 = (vrl << 13) + ((((lane & 15) << 4)) ^ ((4 + vrl) << 4));

        const char* Khb = (const char*)Khp + bS * 128;
        const char* Klb = (const char*)Klp + bS * 128;
        const char* Vhb = (const char*)Vthp + (size_t)b * 64 * 8192;
        const char* Vlb = (const char*)Vtlp + (size_t)b * 64 * 8192;

        auto issue_tile = [&](int kt, int bsel) {
            char* buf = smem + 8192 + bsel * 65536;
            if (w < 4) {
                #pragma unroll
                for (int j = 0; j < 8; ++j) {
                    const int c2  = w * 8 + j;
                    const int p   = c2 >> 4;
                    const int ckp = c2 & 15;
                    const char* g = (p ? Klb : Khb) +
                                    (size_t)kt * 16384 + ckp * 1024 + klaneoff;
                    gload16(g, buf + p * 16384 + ckp * 1024);
                }
            } else {
                #pragma unroll
                for (int j = 0; j < 8; ++j) {
                    const int c2  = (w - 4) * 8 + j;
                    const int p   = c2 >> 4;
                    const int cvp = c2 & 15;
                    const int vo  = (cvp & 1) ? voff1 : voff0;
                    const char* g = (p ? Vlb : Vhb) +
                                    (size_t)cvp * 32768 + (size_t)kt * 256 + vo;
                    gload16(g, buf + 32768 + p * 16384 + cvp * 1024);
                }
            }
        };

        #pragma unroll 1
        for (int hf = 0; hf < 2; ++hf) {
            const int qt = hf ? (127 - pair) : pair;
            const int q0 = qt << 5;
            const int nk = (qt >> 2) + 1;   // pair sum is always 33

            __syncthreads();   // prior phase / half fully done

            {
                const unsigned short* src = qp ? Qlp : Qhp;
                uint4 v = *reinterpret_cast<const uint4*>(
                    src + (bS + q0 + qrow) * 64 + qsg * 8);
                const int off = qp * 4096 + qrow * 128 +
                                ((qsg * 16) ^ ((qrow & 7) << 4));
                *reinterpret_cast<uint4*>(smem + off) = v;
            }
            issue_tile(0, 0);
            __syncthreads();   // Q stores + tile0 DMA complete

            short8b qf[2][2];
            #pragma unroll
            for (int p = 0; p < 2; ++p)
                #pragma unroll
                for (int ks = 0; ks < 2; ++ks) {
                    const int row = qh * 16 + l15;
                    const int off = p * 4096 + row * 128 +
                                    ((ks * 64 + l4 * 16) ^ ((row & 7) << 4));
                    qf[p][ks] = *reinterpret_cast<const short8b*>(smem + off);
                }
            __syncthreads();   // Q reads done before P aliases the region

            f32x4 of[4];
            of[0] = f32x4{0.f, 0.f, 0.f, 0.f};
            of[1] = f32x4{0.f, 0.f, 0.f, 0.f};
            of[2] = f32x4{0.f, 0.f, 0.f, 0.f};
            of[3] = f32x4{0.f, 0.f, 0.f, 0.f};
            float mrun[4], lrun[4];
            #pragma unroll
            for (int r = 0; r < 4; ++r) { mrun[r] = NEG_BIG; lrun[r] = 0.f; }

            #pragma unroll 1
            for (int kt = 0; kt < nk; ++kt) {
                const int bsel = kt & 1;
                if (kt + 1 < nk) issue_tile(kt + 1, bsel ^ 1);

                const char* kb = smem + 8192 + bsel * 65536;
                const char* vb = kb + 32768;

                f32x4 sc[2];
                #pragma unroll
                for (int ct = 0; ct < 2; ++ct) {
                    f32x4 a = f32x4{0.f, 0.f, 0.f, 0.f};
                    #pragma unroll
                    for (int ks = 0; ks < 2; ++ks) {
                        const int row = kh * 32 + ct * 16 + l15;
                        const int off = row * 128 +
                                        ((ks * 64 + l4 * 16) ^ ((row & 7) << 4));
                        short8b bh = *reinterpret_cast<const short8b*>(kb + off);
                        short8b bl = *reinterpret_cast<const short8b*>(kb + 16384 + off);
                        a = MFMA16(qf[1][ks], bh, a);   // qlo * khi
                        a = MFMA16(qf[0][ks], bl, a);   // qhi * klo
                        a = MFMA16(qf[0][ks], bh, a);   // qhi * khi
                    }
                    sc[ct] = a;
                }

                if (kt == nk - 1) {
                    #pragma unroll
                    for (int ct = 0; ct < 2; ++ct) {
                        const int col = kt * 128 + kh * 32 + ct * 16 + l15;
                        #pragma unroll
                        for (int r = 0; r < 4; ++r) {
                            const int row = q0 + qh * 16 + l4 * 4 + r;
                            if (col > row) sc[ct][r] = NEG_BIG;
                        }
                    }
                }

                float pm[4];
                #pragma unroll
                for (int r = 0; r < 4; ++r) pm[r] = fmaxf(sc[0][r], sc[1][r]);
                #pragma unroll
                for (int s = 1; s < 16; s <<= 1)
                    #pragma unroll
                    for (int r = 0; r < 4; ++r)
                        pm[r] = fmaxf(pm[r], __shfl_xor(pm[r], s));

                float alpha[4], ps[4];
                #pragma unroll
                for (int r = 0; r < 4; ++r) {
                    const float mn = fmaxf(fmaxf(mrun[r], pm[r]), MCLAMP);
                    alpha[r] = __expf(mrun[r] - mn);      // first tile: 0
                    mrun[r] = mn;
                    sc[0][r] = __expf(sc[0][r] - mn);     // masked -> 0
                    sc[1][r] = __expf(sc[1][r] - mn);
                    ps[r] = sc[0][r] + sc[1][r];
                }
                #pragma unroll
                for (int s = 1; s < 16; s <<= 1)
                    #pragma unroll
                    for (int r = 0; r < 4; ++r) ps[r] += __shfl_xor(ps[r], s);
                #pragma unroll
                for (int r = 0; r < 4; ++r) lrun[r] = lrun[r] * alpha[r] + ps[r];
                #pragma unroll
                for (int c = 0; c < 4; ++c)
                    #pragma unroll
                    for (int r = 0; r < 4; ++r) of[c][r] *= alpha[r];

                #pragma unroll
                for (int ct = 0; ct < 2; ++ct)
                    #pragma unroll
                    for (int r = 0; r < 4; ++r) {
                        const int row = qh * 16 + l4 * 4 + r;
                        const int col = kh * 32 + ct * 16 + l15;
                        const int off = row * 256 + ((col * 2) ^ ((row & 7) << 4));
                        *reinterpret_cast<unsigned short*>(smem + off) =
                            f2bf_rne(sc[ct][r]);
                    }
                asm volatile("s_waitcnt lgkmcnt(0)" ::: "memory");
                __builtin_amdgcn_sched_barrier(0);

                short8b pf;
                {
                    const int row = qh * 16 + l15;
                    const int off = row * 256 + ((kh * 64 + l4 * 16) ^ ((row & 7) << 4));
                    pf = *reinterpret_cast<const short8b*>(smem + off);
                }
                #pragma unroll
                for (int ct = 0; ct < 4; ++ct) {
                    const int vr = ct * 16 + l15;
                    const int voff = vr * 256 +
                                     ((kh * 64 + l4 * 16) ^ ((vr & 7) << 4));
                    short8b vh = *reinterpret_cast<const short8b*>(vb + voff);
                    short8b vl = *reinterpret_cast<const short8b*>(vb + 16384 + voff);
                    of[ct] = MFMA16(pf, vl, of[ct]);
                    of[ct] = MFMA16(pf, vh, of[ct]);
                }

                __syncthreads();   // end of tile: drains prefetch; orders reuse
            }

            if (l15 == 0) {
                #pragma unroll
                for (int r = 0; r < 4; ++r) {
                    const int row = qh * 16 + l4 * 4 + r;
                    Mg[kh][row] = mrun[r];
                    Lg[kh][row] = lrun[r];
                }
            }
            __syncthreads();

            float* Op = reinterpret_cast<float*>(smem + 8192);
            #pragma unroll
            for (int r = 0; r < 4; ++r) {
                const int row = qh * 16 + l4 * 4 + r;
                const float M = fmaxf(fmaxf(Mg[0][row], Mg[1][row]),
                                      fmaxf(Mg[2][row], Mg[3][row]));
                const float L = Lg[0][row] * __expf(Mg[0][row] - M)
                              + Lg[1][row] * __expf(Mg[1][row] - M)
                              + Lg[2][row] * __expf(Mg[2][row] - M)
                              + Lg[3][row] * __expf(Mg[3][row] - M);
                const float al = __expf(mrun[r] - M);   // empty group -> 0
                #pragma unroll
                for (int c = 0; c < 4; ++c)
                    Op[kh * 2048 + row * 64 + c * 16 + l15] = of[c][r] * al;
                if (kh == 0 && l15 == 0) Ltot[row] = L;
            }
            __syncthreads();

            {
                const int row = (t >> 4) & 31;   // 512 thr -> each (row,d0) once
                const int d0  = (t & 15) << 2;
                float4 s = {0.f, 0.f, 0.f, 0.f};
                #pragma unroll
                for (int g = 0; g < 4; ++g) {
                    float4 v = *reinterpret_cast<const float4*>(
                        Op + g * 2048 + row * 64 + d0);
                    s.x += v.x; s.y += v.y; s.z += v.z; s.w += v.w;
                }
                const float inv = 1.0f / Ltot[row];
                const size_t oi = (bS + q0 + row) * 64 + d0;
                if (t < 512) {
                    if (f32o) {
                        float4 o;
                        o.x = s.x * inv; o.y = s.y * inv;
                        o.z = s.z * inv; o.w = s.w * inv;
                        *reinterpret_cast<float4*>((float*)out + oi) = o;
                    } else {
                        ushort4 o;
                        o.x = f2bf_rne(s.x * inv);
                        o.y = f2bf_rne(s.y * inv);
                        o.z = f2bf_rne(s.z * inv);
                        o.w = f2bf_rne(s.w * inv);
                        *reinterpret_cast<ushort4*>((unsigned short*)out + oi) = o;
                    }
                }
            }
        }
    }
}

extern "C" void kernel_launch(void* const* d_in, const int* in_sizes, int n_in,
                              void* d_out, int out_size, void* d_ws, size_t ws_size,
                              hipStream_t stream) {
    // workspace: 6 bf16 planes (Qh,Ql,Kh,Kl,Vth,Vtl) = 6 x 2MB = 12MB
    const size_t NP = (size_t)B_ * S_ * DH;
    unsigned short* Qhp  = (unsigned short*)d_ws;
    unsigned short* Qlp  = Qhp + NP;
    unsigned short* Khp  = Qhp + 2 * NP;
    unsigned short* Klp  = Qhp + 3 * NP;
    unsigned short* Vthp = Qhp + 4 * NP;
    unsigned short* Vtlp = Qhp + 5 * NP;

    const void* xq = d_in[0]; const void* xk = d_in[1]; const void* xv = d_in[2];
    const void* Wq = d_in[3]; const void* bq = d_in[4];
    const void* Wk = d_in[5]; const void* bk = d_in[6];
    const void* Wv = d_in[7]; const void* bv = d_in[8];
    void* outp = d_out;

    void* args[] = {
        (void*)&xq, (void*)&xk, (void*)&xv,
        (void*)&Wq, (void*)&Wk, (void*)&Wv,
        (void*)&bq, (void*)&bk, (void*)&bv,
        (void*)&Qhp, (void*)&Qlp, (void*)&Khp, (void*)&Klp,
        (void*)&Vthp, (void*)&Vtlp, (void*)&outp
    };
    hipLaunchCooperativeKernel((void*)fused_kernel, dim3(256), dim3(512),
                               args, 0, stream);
}

// Round 8
// 251.931 us; speedup vs baseline: 1.3956x; 1.3956x over previous
//
#include <hip/hip_runtime.h>
#include <hip/hip_bf16.h>

#define B_ 4
#define S_ 4096
#define DM 512
#define DH 64

#define NEG_BIG (-3.0e38f)
#define MCLAMP  (-1.0e30f)

typedef __attribute__((ext_vector_type(8))) short short8b;   // 8 bf16 (4 VGPRs)
typedef __attribute__((ext_vector_type(4))) float f32x4;     // MFMA C/D

__device__ __forceinline__ f32x4 MFMA16(short8b a, short8b b, f32x4 c) {
    return __builtin_amdgcn_mfma_f32_16x16x32_bf16(a, b, c, 0, 0, 0);
}

__device__ __forceinline__ float bf2f(unsigned short u) {
    unsigned int x = ((unsigned int)u) << 16;
    float f;
    __builtin_memcpy(&f, &x, 4);
    return f;
}
__device__ __forceinline__ unsigned short f2bf_rne(float f) {
    unsigned int u = __float_as_uint(f);
    u += 0x7FFFu + ((u >> 16) & 1u);
    return (unsigned short)(u >> 16);
}
__device__ __forceinline__ unsigned int pk2(unsigned short a, unsigned short b) {
    return (unsigned int)a | ((unsigned int)b << 16);
}

// async HBM->LDS DMA, 16B/lane.
__device__ __forceinline__ void gload16(const void* gp, void* lp) {
    __builtin_amdgcn_global_load_lds(
        (const __attribute__((address_space(1))) void*)gp,
        (__attribute__((address_space(3))) void*)lp, 16, 0, 0);
}

// ---------------------------------------------------------------------------
// Projection: bf16 MFMA GEMM with hi/lo split precision (round-6 verified),
// detect folded in as a block-local scan (kills the detect launch + the
// dependent flag load). 768 blocks (~3/CU) -> cross-block overlap hides the
// staging barriers (the mechanism round 7's fusion broke).
// ---------------------------------------------------------------------------
__global__ __launch_bounds__(256) void proj_kernel(
    const void* __restrict__ xq, const void* __restrict__ xk,
    const void* __restrict__ xv,
    const void* __restrict__ Wq, const void* __restrict__ Wk,
    const void* __restrict__ Wv,
    const void* __restrict__ bq, const void* __restrict__ bk,
    const void* __restrict__ bv,
    unsigned short* __restrict__ Qhp, unsigned short* __restrict__ Qlp,
    unsigned short* __restrict__ Khp, unsigned short* __restrict__ Klp,
    unsigned short* __restrict__ Vthp, unsigned short* __restrict__ Vtlp)
{
    const int which = blockIdx.y;
    const void* x    = (which == 0) ? xq : (which == 1) ? xk : xv;
    const void* W    = (which == 0) ? Wq : (which == 1) ? Wk : Wv;
    const void* bias = (which == 0) ? bq : (which == 1) ? bk : bv;

    const int row0 = blockIdx.x * 64;
    const int t    = threadIdx.x;
    const int lane = t & 63;
    const int w    = t >> 6;        // 0..3: wave owns rows w*16..+15
    const int l15  = lane & 15;
    const int l4   = lane >> 4;

    // [0,8192) Xh | [8192,16384) Xl | [16384,24576) Wh | [24576,32768) Wl
    // epilogue alias: float Cbuf[64][66] (16896 B)
    __shared__ __align__(16) char sm[32768];
    __shared__ int sdet;

    // ---- block-local dtype detect (first 2048 halves of q_in) ----
    if (t == 0) sdet = 0;
    __syncthreads();
    {
        const unsigned short* u = (const unsigned short*)xq;
        int cnt = 0;
        #pragma unroll
        for (int k = 0; k < 8; ++k) {
            unsigned short v = u[t * 8 + k];
            int e = (v >> 7) & 0xFF;
            if (e >= 135 || (e > 0 && e <= 95)) ++cnt;
        }
        atomicAdd(&sdet, cnt);
    }
    __syncthreads();
    const bool f32 = (sdet > 64);   // 1 -> fp32 inputs, 0 -> bf16

    const int srow = t >> 2;        // 0..63 (X row / W head)
    const int sseg = t & 3;         // 16-elem segment
    const int swz  = (srow & 7) << 4;
    const int arow = w * 16 + l15;

    f32x4 acc[4];
    #pragma unroll
    for (int n = 0; n < 4; ++n) acc[n] = f32x4{0.f, 0.f, 0.f, 0.f};

    #pragma unroll 1
    for (int kc = 0; kc < DM / 64; ++kc) {
        const int k0 = kc * 64;
        __syncthreads();   // prev chunk's fragment reads complete

        if (f32) {
            #pragma unroll
            for (int m = 0; m < 2; ++m) {   // m=0: X, m=1: W
                const float* p = (m == 0)
                    ? (const float*)x + (size_t)(row0 + srow) * DM + k0 + sseg * 16
                    : (const float*)W + (size_t)srow * DM + k0 + sseg * 16;
                float v[16];
                #pragma unroll
                for (int j = 0; j < 4; ++j) {
                    float4 f = *reinterpret_cast<const float4*>(p + j * 4);
                    v[j*4+0] = f.x; v[j*4+1] = f.y;
                    v[j*4+2] = f.z; v[j*4+3] = f.w;
                }
                unsigned short hh[16], ll[16];
                #pragma unroll
                for (int j = 0; j < 16; ++j) {
                    unsigned short hb = f2bf_rne(v[j]);
                    hh[j] = hb;
                    ll[j] = f2bf_rne(v[j] - bf2f(hb));
                }
                char* dh = sm + m * 16384 + srow * 128;
                char* dl = dh + 8192;
                #pragma unroll
                for (int g = 0; g < 2; ++g) {
                    const int off = (sseg * 32 + g * 16) ^ swz;
                    uint4 hu, lu;
                    hu.x = pk2(hh[g*8+0], hh[g*8+1]); hu.y = pk2(hh[g*8+2], hh[g*8+3]);
                    hu.z = pk2(hh[g*8+4], hh[g*8+5]); hu.w = pk2(hh[g*8+6], hh[g*8+7]);
                    lu.x = pk2(ll[g*8+0], ll[g*8+1]); lu.y = pk2(ll[g*8+2], ll[g*8+3]);
                    lu.z = pk2(ll[g*8+4], ll[g*8+5]); lu.w = pk2(ll[g*8+6], ll[g*8+7]);
                    *reinterpret_cast<uint4*>(dh + off) = hu;
                    *reinterpret_cast<uint4*>(dl + off) = lu;
                }
            }
        } else {
            const uint4 z = {0u, 0u, 0u, 0u};
            #pragma unroll
            for (int m = 0; m < 2; ++m) {
                const unsigned short* p = (m == 0)
                    ? (const unsigned short*)x + (size_t)(row0 + srow) * DM + k0 + sseg * 16
                    : (const unsigned short*)W + (size_t)srow * DM + k0 + sseg * 16;
                char* dh = sm + m * 16384 + srow * 128;
                char* dl = dh + 8192;
                #pragma unroll
                for (int g = 0; g < 2; ++g) {
                    uint4 hv = *reinterpret_cast<const uint4*>(p + g * 8);
                    const int off = (sseg * 32 + g * 16) ^ swz;
                    *reinterpret_cast<uint4*>(dh + off) = hv;
                    *reinterpret_cast<uint4*>(dl + off) = z;   // lo = 0 exact
                }
            }
        }
        __syncthreads();   // stage visible

        short8b xh[2], xl[2];
        #pragma unroll
        for (int ks = 0; ks < 2; ++ks) {
            const int off = arow * 128 + ((ks * 64 + l4 * 16) ^ ((arow & 7) << 4));
            xh[ks] = *reinterpret_cast<const short8b*>(sm + off);
            xl[ks] = *reinterpret_cast<const short8b*>(sm + 8192 + off);
        }
        #pragma unroll
        for (int n = 0; n < 4; ++n) {
            const int brow = n * 16 + l15;
            #pragma unroll
            for (int ks = 0; ks < 2; ++ks) {
                const int off = brow * 128 + ((ks * 64 + l4 * 16) ^ ((brow & 7) << 4));
                short8b wh = *reinterpret_cast<const short8b*>(sm + 16384 + off);
                short8b wl = *reinterpret_cast<const short8b*>(sm + 24576 + off);
                acc[n] = MFMA16(xh[ks], wl, acc[n]);   // xhi * wlo
                acc[n] = MFMA16(xl[ks], wh, acc[n]);   // xlo * whi
                acc[n] = MFMA16(xh[ks], wh, acc[n]);   // xhi * whi
            }
        }
    }

    // ---- epilogue: acc -> LDS f32 C[64][66] -> planes ----
    __syncthreads();   // last chunk frag reads complete
    float* C = reinterpret_cast<float*>(sm);   // [64][66]
    #pragma unroll
    for (int n = 0; n < 4; ++n)
        #pragma unroll
        for (int r = 0; r < 4; ++r)
            C[(w * 16 + l4 * 4 + r) * 66 + n * 16 + l15] = acc[n][r];
    __syncthreads();

    if (which < 2) {
        unsigned short* ph = (which == 0) ? Qhp : Khp;
        unsigned short* pl = (which == 0) ? Qlp : Klp;
        const float scale = (which == 0) ? 0.125f : 1.0f;   // 1/sqrt(64) in Q
        const int r_  = t >> 2;          // local row
        const int c0_ = (t & 3) * 16;    // head segment
        unsigned short hh[16], ll[16];
        #pragma unroll
        for (int j = 0; j < 16; ++j) {
            const float bv_ = f32 ? ((const float*)bias)[c0_ + j]
                                  : bf2f(((const unsigned short*)bias)[c0_ + j]);
            const float v = (C[r_ * 66 + c0_ + j] + bv_) * scale;
            unsigned short hb = f2bf_rne(v);
            hh[j] = hb;
            ll[j] = f2bf_rne(v - bf2f(hb));
        }
        const size_t off = (size_t)(row0 + r_) * DH + c0_;
        #pragma unroll
        for (int g = 0; g < 2; ++g) {
            uint4 hu, lu;
            hu.x = pk2(hh[g*8+0], hh[g*8+1]); hu.y = pk2(hh[g*8+2], hh[g*8+3]);
            hu.z = pk2(hh[g*8+4], hh[g*8+5]); hu.w = pk2(hh[g*8+6], hh[g*8+7]);
            lu.x = pk2(ll[g*8+0], ll[g*8+1]); lu.y = pk2(ll[g*8+2], ll[g*8+3]);
            lu.z = pk2(ll[g*8+4], ll[g*8+5]); lu.w = pk2(ll[g*8+6], ll[g*8+7]);
            *reinterpret_cast<uint4*>(ph + off + g * 8) = hu;
            *reinterpret_cast<uint4*>(pl + off + g * 8) = lu;
        }
    } else {
        const int c_ = t & 63;           // head (= Vt d-row)
        const int rb = (t >> 6) * 16;    // local row block
        const int bb = row0 >> 12;       // batch
        const int s0 = row0 & (S_ - 1);
        const float bv_ = f32 ? ((const float*)bias)[c_]
                              : bf2f(((const unsigned short*)bias)[c_]);
        unsigned short hh[16], ll[16];
        #pragma unroll
        for (int i = 0; i < 16; ++i) {
            const float v = C[(rb + i) * 66 + c_] + bv_;
            unsigned short hb = f2bf_rne(v);
            hh[i] = hb;
            ll[i] = f2bf_rne(v - bf2f(hb));
        }
        const size_t off = (size_t)(bb * 64 + c_) * S_ + s0 + rb;
        #pragma unroll
        for (int g = 0; g < 2; ++g) {
            uint4 hu, lu;
            hu.x = pk2(hh[g*8+0], hh[g*8+1]); hu.y = pk2(hh[g*8+2], hh[g*8+3]);
            hu.z = pk2(hh[g*8+4], hh[g*8+5]); hu.w = pk2(hh[g*8+6], hh[g*8+7]);
            lu.x = pk2(ll[g*8+0], ll[g*8+1]); lu.y = pk2(ll[g*8+2], ll[g*8+3]);
            lu.z = pk2(ll[g*8+4], ll[g*8+5]); lu.w = pk2(ll[g*8+6], ll[g*8+7]);
            *reinterpret_cast<uint4*>(Vthp + off + g * 8) = hu;
            *reinterpret_cast<uint4*>(Vtlp + off + g * 8) = lu;
        }
    }
}

// ---------------------------------------------------------------------------
// Flash attention v6: round-6 algorithm re-tiled for 2 blocks/CU overlap.
//  - 64-key K/V tiles (32 KB/buffer, dbuf) + Q/P 8 KB = 72 KB LDS -> TWO
//    independent blocks per CU. Same 8 waves/CU as round 6, but from two
//    barrier-independent blocks: block A's barrier drain overlaps block B's
//    compute (m114 mechanism; round 7 proved its absence costs ~2x).
//  - 512 blocks x 256 thr (4 waves: qh in {0,1} x kh in {0,1}); one 32-row
//    q-tile per block, DESCENDING work order (qt = 127 - blk/4): LPT
//    scheduling over 2 slots/CU balances to ~1%.
//  - Per-kh-group (32 cols) online softmax + epilogue LSE merge (2 groups),
//    MCLAMP handles fully-masked groups (even-qt last tile, small qt).
//  - All swizzles / fragment addressing / DMA staging identical to round 6.
// ---------------------------------------------------------------------------
__global__ __launch_bounds__(256, 2) void flash_kernel(
    const unsigned short* __restrict__ Qh, const unsigned short* __restrict__ Ql,
    const unsigned short* __restrict__ Kh, const unsigned short* __restrict__ Kl,
    const unsigned short* __restrict__ Vth, const unsigned short* __restrict__ Vtl,
    void* __restrict__ out, const unsigned short* __restrict__ xq_det)
{
    const int blk  = blockIdx.x;
    const int qt   = 127 - (blk >> 2);   // big q-tiles first (LPT)
    const int b    = blk & 3;
    const int t    = threadIdx.x;
    const int lane = t & 63;
    const int w    = t >> 6;             // 0..3
    const int qh   = w & 1;              // q half (16 rows)
    const int kh   = w >> 1;             // key group (32 cols), 0..1
    const int l15  = lane & 15;
    const int l4   = lane >> 4;

    // [0,8192) Q planes / P (alias) | [8192,+32768) buf0 | [40960,+32768) buf1
    // buf: [0,8K) Khi | [8K,16K) Klo | [16K,24K) Vhi | [24K,32K) Vlo
    __shared__ __align__(16) char smem[8192 + 2 * 32768];
    __shared__ float Mg[2][32];
    __shared__ float Lg[2][32];
    __shared__ float Ltot[32];
    __shared__ int sdet;

    // ---- block-local dtype detect ----
    if (t == 0) sdet = 0;
    __syncthreads();
    {
        int cnt = 0;
        #pragma unroll
        for (int k = 0; k < 8; ++k) {
            unsigned short v = xq_det[t * 8 + k];
            int e = (v >> 7) & 0xFF;
            if (e >= 135 || (e > 0 && e <= 95)) ++cnt;
        }
        atomicAdd(&sdet, cnt);
    }
    __syncthreads();
    const bool f32o = (sdet > 64);

    const size_t bS = (size_t)b * S_;
    const int q0 = qt << 5;
    const int nk = (qt >> 1) + 1;       // 64-key tiles

    // staging lane constants: chunk = 8 rows x 128B; source pre-swizzled so
    // linear LDS dest == swizzled layout (rule #21 both-sides involution).
    const int klaneoff = ((lane >> 3) << 7) +
                         ((((lane & 7) << 4)) ^ ((lane >> 3) << 4));
    const int vlaneoff = ((lane >> 3) << 13) +
                         ((((lane & 7) << 4)) ^ ((lane >> 3) << 4));

    const char* Khb = (const char*)Kh + bS * 128;           // 128 B per k-row
    const char* Klb = (const char*)Kl + bS * 128;
    const char* Vhb = (const char*)Vth + (size_t)b * 64 * 8192;  // 8192 B per d-row
    const char* Vlb = (const char*)Vtl + (size_t)b * 64 * 8192;

    auto issue_tile = [&](int kt, int bsel) {
        char* buf = smem + 8192 + bsel * 32768;
        if (w < 2) {
            // K: 16 chunks (2 planes x 8 x 1024B); waves 0,1 x 8 issues
            #pragma unroll
            for (int j = 0; j < 8; ++j) {
                const int c  = w * 8 + j;           // 0..15
                const int p  = c >> 3;
                const int ck = c & 7;
                const char* g = (p ? Klb : Khb) +
                                (size_t)kt * 8192 + ck * 1024 + klaneoff;
                gload16(g, buf + p * 8192 + ck * 1024);
            }
        } else {
            // V: 16 chunks (2 planes x 8); chunk = 8 d-rows x 128B column slice
            #pragma unroll
            for (int j = 0; j < 8; ++j) {
                const int c  = (w - 2) * 8 + j;     // 0..15
                const int p  = c >> 3;
                const int cv = c & 7;
                const char* g = (p ? Vlb : Vhb) +
                                (size_t)cv * 65536 + (size_t)kt * 128 + vlaneoff;
                gload16(g, buf + 16384 + p * 8192 + cv * 1024);
            }
        }
    };

    // ---- stage Q (2 planes, swizzled, 2 stores/thread) ----
    {
        const int qrow = t >> 3;
        const int qsg  = t & 7;
        const size_t goff = (bS + q0 + qrow) * 64 + qsg * 8;
        const int off = qrow * 128 + ((qsg * 16) ^ ((qrow & 7) << 4));
        *reinterpret_cast<uint4*>(smem + off) =
            *reinterpret_cast<const uint4*>(Qh + goff);
        *reinterpret_cast<uint4*>(smem + 4096 + off) =
            *reinterpret_cast<const uint4*>(Ql + goff);
    }
    issue_tile(0, 0);
    __syncthreads();   // Q stores + tile0 DMA complete (vmcnt+lgkm drained)

    short8b qf[2][2];   // [plane][ks]
    #pragma unroll
    for (int p = 0; p < 2; ++p)
        #pragma unroll
        for (int ks = 0; ks < 2; ++ks) {
            const int row = qh * 16 + l15;
            const int off = p * 4096 + row * 128 +
                            ((ks * 64 + l4 * 16) ^ ((row & 7) << 4));
            qf[p][ks] = *reinterpret_cast<const short8b*>(smem + off);
        }
    __syncthreads();   // Q reads done before P aliases the region

    f32x4 of[4];
    of[0] = f32x4{0.f, 0.f, 0.f, 0.f};
    of[1] = f32x4{0.f, 0.f, 0.f, 0.f};
    of[2] = f32x4{0.f, 0.f, 0.f, 0.f};
    of[3] = f32x4{0.f, 0.f, 0.f, 0.f};
    float mrun[4], lrun[4];
    #pragma unroll
    for (int r = 0; r < 4; ++r) { mrun[r] = NEG_BIG; lrun[r] = 0.f; }

    #pragma unroll 1
    for (int kt = 0; kt < nk; ++kt) {
        const int bsel = kt & 1;
        if (kt + 1 < nk) issue_tile(kt + 1, bsel ^ 1);   // async prefetch

        const char* kb = smem + 8192 + bsel * 32768;
        const char* vb = kb + 16384;

        // ---- QK: 3-pass split-precision MFMA over this wave's 32 cols ----
        f32x4 sc[2];
        #pragma unroll
        for (int ct = 0; ct < 2; ++ct) {
            f32x4 a = f32x4{0.f, 0.f, 0.f, 0.f};
            #pragma unroll
            for (int ks = 0; ks < 2; ++ks) {
                const int row = kh * 32 + ct * 16 + l15;
                const int off = row * 128 +
                                ((ks * 64 + l4 * 16) ^ ((row & 7) << 4));
                short8b bh = *reinterpret_cast<const short8b*>(kb + off);
                short8b bl = *reinterpret_cast<const short8b*>(kb + 8192 + off);
                a = MFMA16(qf[1][ks], bh, a);   // qlo * khi
                a = MFMA16(qf[0][ks], bl, a);   // qhi * klo
                a = MFMA16(qf[0][ks], bh, a);   // qhi * khi
            }
            sc[ct] = a;
        }

        // causal mask: only the final k-tile
        if (kt == nk - 1) {
            #pragma unroll
            for (int ct = 0; ct < 2; ++ct) {
                const int col = kt * 64 + kh * 32 + ct * 16 + l15;
                #pragma unroll
                for (int r = 0; r < 4; ++r) {
                    const int row = q0 + qh * 16 + l4 * 4 + r;
                    if (col > row) sc[ct][r] = NEG_BIG;
                }
            }
        }

        // ---- wave-local online softmax (per kh group) ----
        float pm[4];
        #pragma unroll
        for (int r = 0; r < 4; ++r) pm[r] = fmaxf(sc[0][r], sc[1][r]);
        #pragma unroll
        for (int s = 1; s < 16; s <<= 1)
            #pragma unroll
            for (int r = 0; r < 4; ++r)
                pm[r] = fmaxf(pm[r], __shfl_xor(pm[r], s));

        float alpha[4], ps[4];
        #pragma unroll
        for (int r = 0; r < 4; ++r) {
            const float mn = fmaxf(fmaxf(mrun[r], pm[r]), MCLAMP);
            alpha[r] = __expf(mrun[r] - mn);      // first tile: 0
            mrun[r] = mn;
            sc[0][r] = __expf(sc[0][r] - mn);     // masked -> 0 (mn >= -1e30)
            sc[1][r] = __expf(sc[1][r] - mn);
            ps[r] = sc[0][r] + sc[1][r];
        }
        #pragma unroll
        for (int s = 1; s < 16; s <<= 1)
            #pragma unroll
            for (int r = 0; r < 4; ++r) ps[r] += __shfl_xor(ps[r], s);
        #pragma unroll
        for (int r = 0; r < 4; ++r) lrun[r] = lrun[r] * alpha[r] + ps[r];
        #pragma unroll
        for (int c = 0; c < 4; ++c)
            #pragma unroll
            for (int r = 0; r < 4; ++r) of[c][r] *= alpha[r];

        // ---- P write (bf16, wave-private 16x32 block, swizzled) ----
        #pragma unroll
        for (int ct = 0; ct < 2; ++ct)
            #pragma unroll
            for (int r = 0; r < 4; ++r) {
                const int row = qh * 16 + l4 * 4 + r;
                const int col = kh * 32 + ct * 16 + l15;
                const int off = row * 128 + ((col * 2) ^ ((row & 7) << 4));
                *reinterpret_cast<unsigned short*>(smem + off) =
                    f2bf_rne(sc[ct][r]);
            }
        asm volatile("s_waitcnt lgkmcnt(0)" ::: "memory");
        __builtin_amdgcn_sched_barrier(0);

        // ---- P read (own block) + PV ----
        short8b pf;
        {
            const int row = qh * 16 + l15;
            const int off = row * 128 + ((kh * 64 + l4 * 16) ^ ((row & 7) << 4));
            pf = *reinterpret_cast<const short8b*>(smem + off);
        }
        #pragma unroll
        for (int ct = 0; ct < 4; ++ct) {
            const int vr = ct * 16 + l15;   // d-row of Vt
            const int voff = vr * 128 +
                             ((kh * 64 + l4 * 16) ^ ((vr & 7) << 4));
            short8b vh = *reinterpret_cast<const short8b*>(vb + voff);
            short8b vl = *reinterpret_cast<const short8b*>(vb + 8192 + voff);
            of[ct] = MFMA16(pf, vl, of[ct]);
            of[ct] = MFMA16(pf, vh, of[ct]);
        }

        __syncthreads();   // end of tile: drains prefetch; orders LDS reuse
    }

    // ---- epilogue: merge the 2 independent kh groups (LSE) ----
    if (l15 == 0) {
        #pragma unroll
        for (int r = 0; r < 4; ++r) {
            const int row = qh * 16 + l4 * 4 + r;
            Mg[kh][row] = mrun[r];
            Lg[kh][row] = lrun[r];
        }
    }
    __syncthreads();   // stats visible; buffers free for Opart

    float* Op = reinterpret_cast<float*>(smem + 8192);   // 16 KB alias of buf0
    #pragma unroll
    for (int r = 0; r < 4; ++r) {
        const int row = qh * 16 + l4 * 4 + r;
        const float M = fmaxf(Mg[0][row], Mg[1][row]);
        const float L = Lg[0][row] * __expf(Mg[0][row] - M)
                      + Lg[1][row] * __expf(Mg[1][row] - M);
        const float al = __expf(mrun[r] - M);   // empty group -> 0
        #pragma unroll
        for (int c = 0; c < 4; ++c)
            Op[kh * 2048 + row * 64 + c * 16 + l15] = of[c][r] * al;
        if (kh == 0 && l15 == 0) Ltot[row] = L;
    }
    __syncthreads();

    // final reduce across groups + store (8 floats per thread)
    {
        const int row = t >> 3;
        const int d0  = (t & 7) << 3;
        float s[8];
        #pragma unroll
        for (int j = 0; j < 2; ++j) {
            float4 a = *reinterpret_cast<const float4*>(Op + row * 64 + d0 + j * 4);
            float4 c = *reinterpret_cast<const float4*>(Op + 2048 + row * 64 + d0 + j * 4);
            s[j*4+0] = a.x + c.x; s[j*4+1] = a.y + c.y;
            s[j*4+2] = a.z + c.z; s[j*4+3] = a.w + c.w;
        }
        const float inv = 1.0f / Ltot[row];
        const size_t oi = (bS + q0 + row) * 64 + d0;
        if (f32o) {
            float* op = (float*)out + oi;
            #pragma unroll
            for (int j = 0; j < 2; ++j) {
                float4 o;
                o.x = s[j*4+0] * inv; o.y = s[j*4+1] * inv;
                o.z = s[j*4+2] * inv; o.w = s[j*4+3] * inv;
                *reinterpret_cast<float4*>(op + j * 4) = o;
            }
        } else {
            unsigned short hh[8];
            #pragma unroll
            for (int j = 0; j < 8; ++j) hh[j] = f2bf_rne(s[j] * inv);
            uint4 o;
            o.x = pk2(hh[0], hh[1]); o.y = pk2(hh[2], hh[3]);
            o.z = pk2(hh[4], hh[5]); o.w = pk2(hh[6], hh[7]);
            *reinterpret_cast<uint4*>((unsigned short*)out + oi) = o;
        }
    }
}

extern "C" void kernel_launch(void* const* d_in, const int* in_sizes, int n_in,
                              void* d_out, int out_size, void* d_ws, size_t ws_size,
                              hipStream_t stream) {
    // workspace: 6 bf16 planes (Qh,Ql,Kh,Kl,Vth,Vtl) = 6 x 2MB = 12MB
    const size_t NP = (size_t)B_ * S_ * DH;
    unsigned short* Qhp  = (unsigned short*)d_ws;
    unsigned short* Qlp  = Qhp + NP;
    unsigned short* Khp  = Qhp + 2 * NP;
    unsigned short* Klp  = Qhp + 3 * NP;
    unsigned short* Vthp = Qhp + 4 * NP;
    unsigned short* Vtlp = Qhp + 5 * NP;

    proj_kernel<<<dim3(B_ * S_ / 64, 3), 256, 0, stream>>>(
        d_in[0], d_in[1], d_in[2],   // xq, xk, xv
        d_in[3], d_in[5], d_in[7],   // Wq, Wk, Wv
        d_in[4], d_in[6], d_in[8],   // bq, bk, bv
        Qhp, Qlp, Khp, Klp, Vthp, Vtlp);

    flash_kernel<<<dim3(512), 256, 0, stream>>>(
        Qhp, Qlp, Khp, Klp, Vthp, Vtlp, d_out,
        (const unsigned short*)d_in[0]);
}

// Round 9
// 215.839 us; speedup vs baseline: 1.6290x; 1.1672x over previous
//
#include <hip/hip_runtime.h>
#include <hip/hip_bf16.h>

#define B_ 4
#define S_ 4096
#define DM 512
#define DH 64

#define NEG_BIG (-3.0e38f)
#define MCLAMP  (-1.0e30f)

typedef __attribute__((ext_vector_type(8))) short short8b;   // 8 bf16 (4 VGPRs)
typedef __attribute__((ext_vector_type(4))) float f32x4;     // MFMA C/D

__device__ __forceinline__ f32x4 MFMA16(short8b a, short8b b, f32x4 c) {
    return __builtin_amdgcn_mfma_f32_16x16x32_bf16(a, b, c, 0, 0, 0);
}

__device__ __forceinline__ float bf2f(unsigned short u) {
    unsigned int x = ((unsigned int)u) << 16;
    float f;
    __builtin_memcpy(&f, &x, 4);
    return f;
}
__device__ __forceinline__ unsigned short f2bf_rne(float f) {
    unsigned int u = __float_as_uint(f);
    u += 0x7FFFu + ((u >> 16) & 1u);
    return (unsigned short)(u >> 16);
}
__device__ __forceinline__ unsigned int pk2(unsigned short a, unsigned short b) {
    return (unsigned int)a | ((unsigned int)b << 16);
}

// async HBM->LDS DMA, 16B/lane.
__device__ __forceinline__ void gload16(const void* gp, void* lp) {
    __builtin_amdgcn_global_load_lds(
        (const __attribute__((address_space(1))) void*)gp,
        (__attribute__((address_space(3))) void*)lp, 16, 0, 0);
}

// ---------------------------------------------------------------------------
// Projection: bf16 MFMA GEMM, hi/lo split precision, detect folded in.
// Round-8-verified, with Vt_lo plane writes DROPPED (flash no longer reads
// it: P-bf16 quantization already dominates the output error budget).
// ---------------------------------------------------------------------------
__global__ __launch_bounds__(256) void proj_kernel(
    const void* __restrict__ xq, const void* __restrict__ xk,
    const void* __restrict__ xv,
    const void* __restrict__ Wq, const void* __restrict__ Wk,
    const void* __restrict__ Wv,
    const void* __restrict__ bq, const void* __restrict__ bk,
    const void* __restrict__ bv,
    unsigned short* __restrict__ Qhp, unsigned short* __restrict__ Qlp,
    unsigned short* __restrict__ Khp, unsigned short* __restrict__ Klp,
    unsigned short* __restrict__ Vthp)
{
    const int which = blockIdx.y;
    const void* x    = (which == 0) ? xq : (which == 1) ? xk : xv;
    const void* W    = (which == 0) ? Wq : (which == 1) ? Wk : Wv;
    const void* bias = (which == 0) ? bq : (which == 1) ? bk : bv;

    const int row0 = blockIdx.x * 64;
    const int t    = threadIdx.x;
    const int lane = t & 63;
    const int w    = t >> 6;        // 0..3: wave owns rows w*16..+15
    const int l15  = lane & 15;
    const int l4   = lane >> 4;

    // [0,8192) Xh | [8192,16384) Xl | [16384,24576) Wh | [24576,32768) Wl
    // epilogue alias: float Cbuf[64][66] (16896 B)
    __shared__ __align__(16) char sm[32768];
    __shared__ int sdet;

    // ---- block-local dtype detect (first 2048 halves of q_in) ----
    if (t == 0) sdet = 0;
    __syncthreads();
    {
        const unsigned short* u = (const unsigned short*)xq;
        int cnt = 0;
        #pragma unroll
        for (int k = 0; k < 8; ++k) {
            unsigned short v = u[t * 8 + k];
            int e = (v >> 7) & 0xFF;
            if (e >= 135 || (e > 0 && e <= 95)) ++cnt;
        }
        atomicAdd(&sdet, cnt);
    }
    __syncthreads();
    const bool f32 = (sdet > 64);   // 1 -> fp32 inputs, 0 -> bf16

    const int srow = t >> 2;        // 0..63 (X row / W head)
    const int sseg = t & 3;         // 16-elem segment
    const int swz  = (srow & 7) << 4;
    const int arow = w * 16 + l15;

    f32x4 acc[4];
    #pragma unroll
    for (int n = 0; n < 4; ++n) acc[n] = f32x4{0.f, 0.f, 0.f, 0.f};

    #pragma unroll 1
    for (int kc = 0; kc < DM / 64; ++kc) {
        const int k0 = kc * 64;
        __syncthreads();   // prev chunk's fragment reads complete

        if (f32) {
            #pragma unroll
            for (int m = 0; m < 2; ++m) {   // m=0: X, m=1: W
                const float* p = (m == 0)
                    ? (const float*)x + (size_t)(row0 + srow) * DM + k0 + sseg * 16
                    : (const float*)W + (size_t)srow * DM + k0 + sseg * 16;
                float v[16];
                #pragma unroll
                for (int j = 0; j < 4; ++j) {
                    float4 f = *reinterpret_cast<const float4*>(p + j * 4);
                    v[j*4+0] = f.x; v[j*4+1] = f.y;
                    v[j*4+2] = f.z; v[j*4+3] = f.w;
                }
                unsigned short hh[16], ll[16];
                #pragma unroll
                for (int j = 0; j < 16; ++j) {
                    unsigned short hb = f2bf_rne(v[j]);
                    hh[j] = hb;
                    ll[j] = f2bf_rne(v[j] - bf2f(hb));
                }
                char* dh = sm + m * 16384 + srow * 128;
                char* dl = dh + 8192;
                #pragma unroll
                for (int g = 0; g < 2; ++g) {
                    const int off = (sseg * 32 + g * 16) ^ swz;
                    uint4 hu, lu;
                    hu.x = pk2(hh[g*8+0], hh[g*8+1]); hu.y = pk2(hh[g*8+2], hh[g*8+3]);
                    hu.z = pk2(hh[g*8+4], hh[g*8+5]); hu.w = pk2(hh[g*8+6], hh[g*8+7]);
                    lu.x = pk2(ll[g*8+0], ll[g*8+1]); lu.y = pk2(ll[g*8+2], ll[g*8+3]);
                    lu.z = pk2(ll[g*8+4], ll[g*8+5]); lu.w = pk2(ll[g*8+6], ll[g*8+7]);
                    *reinterpret_cast<uint4*>(dh + off) = hu;
                    *reinterpret_cast<uint4*>(dl + off) = lu;
                }
            }
        } else {
            const uint4 z = {0u, 0u, 0u, 0u};
            #pragma unroll
            for (int m = 0; m < 2; ++m) {
                const unsigned short* p = (m == 0)
                    ? (const unsigned short*)x + (size_t)(row0 + srow) * DM + k0 + sseg * 16
                    : (const unsigned short*)W + (size_t)srow * DM + k0 + sseg * 16;
                char* dh = sm + m * 16384 + srow * 128;
                char* dl = dh + 8192;
                #pragma unroll
                for (int g = 0; g < 2; ++g) {
                    uint4 hv = *reinterpret_cast<const uint4*>(p + g * 8);
                    const int off = (sseg * 32 + g * 16) ^ swz;
                    *reinterpret_cast<uint4*>(dh + off) = hv;
                    *reinterpret_cast<uint4*>(dl + off) = z;   // lo = 0 exact
                }
            }
        }
        __syncthreads();   // stage visible

        short8b xh[2], xl[2];
        #pragma unroll
        for (int ks = 0; ks < 2; ++ks) {
            const int off = arow * 128 + ((ks * 64 + l4 * 16) ^ ((arow & 7) << 4));
            xh[ks] = *reinterpret_cast<const short8b*>(sm + off);
            xl[ks] = *reinterpret_cast<const short8b*>(sm + 8192 + off);
        }
        #pragma unroll
        for (int n = 0; n < 4; ++n) {
            const int brow = n * 16 + l15;
            #pragma unroll
            for (int ks = 0; ks < 2; ++ks) {
                const int off = brow * 128 + ((ks * 64 + l4 * 16) ^ ((brow & 7) << 4));
                short8b wh = *reinterpret_cast<const short8b*>(sm + 16384 + off);
                short8b wl = *reinterpret_cast<const short8b*>(sm + 24576 + off);
                acc[n] = MFMA16(xh[ks], wl, acc[n]);   // xhi * wlo
                acc[n] = MFMA16(xl[ks], wh, acc[n]);   // xlo * whi
                acc[n] = MFMA16(xh[ks], wh, acc[n]);   // xhi * whi
            }
        }
    }

    // ---- epilogue: acc -> LDS f32 C[64][66] -> planes ----
    __syncthreads();   // last chunk frag reads complete
    float* C = reinterpret_cast<float*>(sm);   // [64][66]
    #pragma unroll
    for (int n = 0; n < 4; ++n)
        #pragma unroll
        for (int r = 0; r < 4; ++r)
            C[(w * 16 + l4 * 4 + r) * 66 + n * 16 + l15] = acc[n][r];
    __syncthreads();

    if (which < 2) {
        unsigned short* ph = (which == 0) ? Qhp : Khp;
        unsigned short* pl = (which == 0) ? Qlp : Klp;
        const float scale = (which == 0) ? 0.125f : 1.0f;   // 1/sqrt(64) in Q
        const int r_  = t >> 2;          // local row
        const int c0_ = (t & 3) * 16;    // head segment
        unsigned short hh[16], ll[16];
        #pragma unroll
        for (int j = 0; j < 16; ++j) {
            const float bv_ = f32 ? ((const float*)bias)[c0_ + j]
                                  : bf2f(((const unsigned short*)bias)[c0_ + j]);
            const float v = (C[r_ * 66 + c0_ + j] + bv_) * scale;
            unsigned short hb = f2bf_rne(v);
            hh[j] = hb;
            ll[j] = f2bf_rne(v - bf2f(hb));
        }
        const size_t off = (size_t)(row0 + r_) * DH + c0_;
        #pragma unroll
        for (int g = 0; g < 2; ++g) {
            uint4 hu, lu;
            hu.x = pk2(hh[g*8+0], hh[g*8+1]); hu.y = pk2(hh[g*8+2], hh[g*8+3]);
            hu.z = pk2(hh[g*8+4], hh[g*8+5]); hu.w = pk2(hh[g*8+6], hh[g*8+7]);
            lu.x = pk2(ll[g*8+0], ll[g*8+1]); lu.y = pk2(ll[g*8+2], ll[g*8+3]);
            lu.z = pk2(ll[g*8+4], ll[g*8+5]); lu.w = pk2(ll[g*8+6], ll[g*8+7]);
            *reinterpret_cast<uint4*>(ph + off + g * 8) = hu;
            *reinterpret_cast<uint4*>(pl + off + g * 8) = lu;
        }
    } else {
        const int c_ = t & 63;           // head (= Vt d-row)
        const int rb = (t >> 6) * 16;    // local row block
        const int bb = row0 >> 12;       // batch
        const int s0 = row0 & (S_ - 1);
        const float bv_ = f32 ? ((const float*)bias)[c_]
                              : bf2f(((const unsigned short*)bias)[c_]);
        unsigned short hh[16];
        #pragma unroll
        for (int i = 0; i < 16; ++i)
            hh[i] = f2bf_rne(C[(rb + i) * 66 + c_] + bv_);   // hi plane only
        const size_t off = (size_t)(bb * 64 + c_) * S_ + s0 + rb;
        #pragma unroll
        for (int g = 0; g < 2; ++g) {
            uint4 hu;
            hu.x = pk2(hh[g*8+0], hh[g*8+1]); hu.y = pk2(hh[g*8+2], hh[g*8+3]);
            hu.z = pk2(hh[g*8+4], hh[g*8+5]); hu.w = pk2(hh[g*8+6], hh[g*8+7]);
            *reinterpret_cast<uint4*>(Vthp + off + g * 8) = hu;
        }
    }
}

// ---------------------------------------------------------------------------
// Flash attention v7 = round-6 verified structure (8 waves, 32q x 128k tiles,
// balanced pairing, DMA-staged dbuf) with the V_lo plane REMOVED:
//  - PV = P(bf16) x V_hi only (P quantization already dominates error);
//    per wave-tile: MFMA 20 -> 16, V-frag LDS reads 8 -> 4, V DMA halved.
//  - buffers 64 -> 48 KB (Khi 16K | Klo 16K | Vhi 16K), LDS 137 -> 105 KB.
//  - detect folded in (block-local scan; no flag kernel).
// ---------------------------------------------------------------------------
__global__ __launch_bounds__(512, 1) void flash_kernel(
    const unsigned short* __restrict__ Qh, const unsigned short* __restrict__ Ql,
    const unsigned short* __restrict__ Kh, const unsigned short* __restrict__ Kl,
    const unsigned short* __restrict__ Vth,
    void* __restrict__ out, const unsigned short* __restrict__ xq_det)
{
    const int pair = blockIdx.x;   // 0..63
    const int b    = blockIdx.y;   // 0..3
    const int t    = threadIdx.x;
    const int lane = t & 63;
    const int w    = t >> 6;       // 0..7
    const int qh   = w & 1;        // q half (16 rows)
    const int kh   = w >> 1;       // key group (32 cols)
    const int l15  = lane & 15;
    const int l4   = lane >> 4;

    // [0,8192) Q planes / P (alias) | buf0 [8192,+49152) | buf1 [57344,+49152)
    // buf: [0,16K) Khi | [16K,32K) Klo | [32K,48K) Vhi
    __shared__ __align__(16) char smem[8192 + 2 * 49152];
    __shared__ float Mg[4][32];
    __shared__ float Lg[4][32];
    __shared__ float Ltot[32];
    __shared__ int sdet;

    // ---- block-local dtype detect ----
    if (t == 0) sdet = 0;
    __syncthreads();
    if (t < 256) {
        int cnt = 0;
        #pragma unroll
        for (int k = 0; k < 8; ++k) {
            unsigned short v = xq_det[t * 8 + k];
            int e = (v >> 7) & 0xFF;
            if (e >= 135 || (e > 0 && e <= 95)) ++cnt;
        }
        atomicAdd(&sdet, cnt);
    }
    __syncthreads();
    const bool f32o = (sdet > 64);

    const size_t bS = (size_t)b * S_;

    // Q staging map (per-thread stores, 1 uint4 each)
    const int qp   = t >> 8;            // plane
    const int qrow = (t & 255) >> 3;    // 0..31
    const int qsg  = t & 7;

    // K staging lane constants: chunk = 8 rows x 128B; source pre-swizzled.
    const int klaneoff = ((lane >> 3) << 7) +
                         ((((lane & 7) << 4)) ^ ((lane >> 3) << 4));
    // V staging lane constants: chunk = 4 rows x 256B; row parity par=cvp&1.
    const int vrl = lane >> 4;          // 0..3
    const int voff0 = (vrl << 13) + ((((lane & 15) << 4)) ^ (vrl << 4));
    const int voff1 = (vrl << 13) + ((((lane & 15) << 4)) ^ ((4 + vrl) << 4));

    const char* Khb = (const char*)Kh + bS * 128;          // 128 B per row
    const char* Klb = (const char*)Kl + bS * 128;
    const char* Vhb = (const char*)Vth + (size_t)b * 64 * 8192;  // 8192 B per d-row

    auto issue_tile = [&](int kt, int bsel) {
        char* buf = smem + 8192 + bsel * 49152;
        if (w < 4) {
            // K: 32 chunks (2 planes x 16), waves 0..3 x 8 issues
            #pragma unroll
            for (int j = 0; j < 8; ++j) {
                const int c2  = w * 8 + j;          // 0..31
                const int p   = c2 >> 4;
                const int ckp = c2 & 15;
                const char* g = (p ? Klb : Khb) +
                                (size_t)kt * 16384 + ckp * 1024 + klaneoff;
                gload16(g, buf + p * 16384 + ckp * 1024);
            }
        } else {
            // V_hi: 16 chunks, waves 4..7 x 4 issues
            #pragma unroll
            for (int j = 0; j < 4; ++j) {
                const int cvp = (w - 4) * 4 + j;    // 0..15
                const int vo  = (cvp & 1) ? voff1 : voff0;
                const char* g = Vhb + (size_t)cvp * 32768 + (size_t)kt * 256 + vo;
                gload16(g, buf + 32768 + cvp * 1024);
            }
        }
    };

    #pragma unroll 1
    for (int hf = 0; hf < 2; ++hf) {
        const int qt = hf ? (127 - pair) : pair;
        const int q0 = qt << 5;
        const int nk = (qt >> 2) + 1;   // 128-key tiles; pair sum is 33

        __syncthreads();   // prior half fully done

        {
            const unsigned short* src = qp ? Ql : Qh;
            uint4 v = *reinterpret_cast<const uint4*>(
                src + (bS + q0 + qrow) * 64 + qsg * 8);
            const int off = qp * 4096 + qrow * 128 +
                            ((qsg * 16) ^ ((qrow & 7) << 4));
            *reinterpret_cast<uint4*>(smem + off) = v;
        }
        issue_tile(0, 0);
        __syncthreads();   // Q stores + tile0 DMA complete

        short8b qf[2][2];   // [plane][ks]
        #pragma unroll
        for (int p = 0; p < 2; ++p)
            #pragma unroll
            for (int ks = 0; ks < 2; ++ks) {
                const int row = qh * 16 + l15;
                const int off = p * 4096 + row * 128 +
                                ((ks * 64 + l4 * 16) ^ ((row & 7) << 4));
                qf[p][ks] = *reinterpret_cast<const short8b*>(smem + off);
            }
        __syncthreads();   // Q reads done before P aliases the region

        f32x4 of[4];
        of[0] = f32x4{0.f, 0.f, 0.f, 0.f};
        of[1] = f32x4{0.f, 0.f, 0.f, 0.f};
        of[2] = f32x4{0.f, 0.f, 0.f, 0.f};
        of[3] = f32x4{0.f, 0.f, 0.f, 0.f};
        float mrun[4], lrun[4];
        #pragma unroll
        for (int r = 0; r < 4; ++r) { mrun[r] = NEG_BIG; lrun[r] = 0.f; }

        #pragma unroll 1
        for (int kt = 0; kt < nk; ++kt) {
            const int bsel = kt & 1;
            if (kt + 1 < nk) issue_tile(kt + 1, bsel ^ 1);   // async prefetch

            const char* kb = smem + 8192 + bsel * 49152;
            const char* vb = kb + 32768;

            // ---- QK: 3-pass split-precision MFMA ----
            f32x4 sc[2];
            #pragma unroll
            for (int ct = 0; ct < 2; ++ct) {
                f32x4 a = f32x4{0.f, 0.f, 0.f, 0.f};
                #pragma unroll
                for (int ks = 0; ks < 2; ++ks) {
                    const int row = kh * 32 + ct * 16 + l15;
                    const int off = row * 128 +
                                    ((ks * 64 + l4 * 16) ^ ((row & 7) << 4));
                    short8b bh = *reinterpret_cast<const short8b*>(kb + off);
                    short8b bl = *reinterpret_cast<const short8b*>(kb + 16384 + off);
                    a = MFMA16(qf[1][ks], bh, a);   // qlo * khi
                    a = MFMA16(qf[0][ks], bl, a);   // qhi * klo
                    a = MFMA16(qf[0][ks], bh, a);   // qhi * khi
                }
                sc[ct] = a;
            }

            // causal mask: only the final k-tile
            if (kt == nk - 1) {
                #pragma unroll
                for (int ct = 0; ct < 2; ++ct) {
                    const int col = kt * 128 + kh * 32 + ct * 16 + l15;
                    #pragma unroll
                    for (int r = 0; r < 4; ++r) {
                        const int row = q0 + qh * 16 + l4 * 4 + r;
                        if (col > row) sc[ct][r] = NEG_BIG;
                    }
                }
            }

            // ---- wave-local online softmax (per kh group) ----
            float pm[4];
            #pragma unroll
            for (int r = 0; r < 4; ++r) pm[r] = fmaxf(sc[0][r], sc[1][r]);
            #pragma unroll
            for (int s = 1; s < 16; s <<= 1)
                #pragma unroll
                for (int r = 0; r < 4; ++r)
                    pm[r] = fmaxf(pm[r], __shfl_xor(pm[r], s));

            float alpha[4], ps[4];
            #pragma unroll
            for (int r = 0; r < 4; ++r) {
                const float mn = fmaxf(fmaxf(mrun[r], pm[r]), MCLAMP);
                alpha[r] = __expf(mrun[r] - mn);      // first tile: 0
                mrun[r] = mn;
                sc[0][r] = __expf(sc[0][r] - mn);     // masked -> 0
                sc[1][r] = __expf(sc[1][r] - mn);
                ps[r] = sc[0][r] + sc[1][r];
            }
            #pragma unroll
            for (int s = 1; s < 16; s <<= 1)
                #pragma unroll
                for (int r = 0; r < 4; ++r) ps[r] += __shfl_xor(ps[r], s);
            #pragma unroll
            for (int r = 0; r < 4; ++r) lrun[r] = lrun[r] * alpha[r] + ps[r];
            #pragma unroll
            for (int c = 0; c < 4; ++c)
                #pragma unroll
                for (int r = 0; r < 4; ++r) of[c][r] *= alpha[r];

            // ---- P write (bf16, wave-private 16x32 block, swizzled) ----
            #pragma unroll
            for (int ct = 0; ct < 2; ++ct)
                #pragma unroll
                for (int r = 0; r < 4; ++r) {
                    const int row = qh * 16 + l4 * 4 + r;
                    const int col = kh * 32 + ct * 16 + l15;
                    const int off = row * 256 + ((col * 2) ^ ((row & 7) << 4));
                    *reinterpret_cast<unsigned short*>(smem + off) =
                        f2bf_rne(sc[ct][r]);
                }
            asm volatile("s_waitcnt lgkmcnt(0)" ::: "memory");
            __builtin_amdgcn_sched_barrier(0);

            // ---- P read (own block) + PV (V_hi only) ----
            short8b pf;
            {
                const int row = qh * 16 + l15;
                const int off = row * 256 + ((kh * 64 + l4 * 16) ^ ((row & 7) << 4));
                pf = *reinterpret_cast<const short8b*>(smem + off);
            }
            #pragma unroll
            for (int ct = 0; ct < 4; ++ct) {
                const int vr = ct * 16 + l15;   // d-row of Vt
                const int voff = vr * 256 +
                                 ((kh * 64 + l4 * 16) ^ ((vr & 7) << 4));
                short8b vh = *reinterpret_cast<const short8b*>(vb + voff);
                of[ct] = MFMA16(pf, vh, of[ct]);
            }

            __syncthreads();   // end of tile: drains prefetch; orders reuse
        }

        // ---- epilogue: merge the 4 independent kh groups (LSE) ----
        if (l15 == 0) {
            #pragma unroll
            for (int r = 0; r < 4; ++r) {
                const int row = qh * 16 + l4 * 4 + r;
                Mg[kh][row] = mrun[r];
                Lg[kh][row] = lrun[r];
            }
        }
        __syncthreads();

        float* Op = reinterpret_cast<float*>(smem + 8192);   // 32 KB alias
        #pragma unroll
        for (int r = 0; r < 4; ++r) {
            const int row = qh * 16 + l4 * 4 + r;
            const float M = fmaxf(fmaxf(Mg[0][row], Mg[1][row]),
                                  fmaxf(Mg[2][row], Mg[3][row]));
            const float L = Lg[0][row] * __expf(Mg[0][row] - M)
                          + Lg[1][row] * __expf(Mg[1][row] - M)
                          + Lg[2][row] * __expf(Mg[2][row] - M)
                          + Lg[3][row] * __expf(Mg[3][row] - M);
            const float al = __expf(mrun[r] - M);   // empty group -> 0
            #pragma unroll
            for (int c = 0; c < 4; ++c)
                Op[kh * 2048 + row * 64 + c * 16 + l15] = of[c][r] * al;
            if (kh == 0 && l15 == 0) Ltot[row] = L;
        }
        __syncthreads();

        {
            const int row = (t >> 4) & 31;   // 512 thr -> each (row,d0) once
            const int d0  = (t & 15) << 2;
            float4 s = {0.f, 0.f, 0.f, 0.f};
            #pragma unroll
            for (int g = 0; g < 4; ++g) {
                float4 v = *reinterpret_cast<const float4*>(
                    Op + g * 2048 + row * 64 + d0);
                s.x += v.x; s.y += v.y; s.z += v.z; s.w += v.w;
            }
            const float inv = 1.0f / Ltot[row];
            const size_t oi = (bS + q0 + row) * 64 + d0;
            if (f32o) {
                float4 o;
                o.x = s.x * inv; o.y = s.y * inv;
                o.z = s.z * inv; o.w = s.w * inv;
                *reinterpret_cast<float4*>((float*)out + oi) = o;
            } else {
                ushort4 o;
                o.x = f2bf_rne(s.x * inv);
                o.y = f2bf_rne(s.y * inv);
                o.z = f2bf_rne(s.z * inv);
                o.w = f2bf_rne(s.w * inv);
                *reinterpret_cast<ushort4*>((unsigned short*)out + oi) = o;
            }
        }
    }
}

extern "C" void kernel_launch(void* const* d_in, const int* in_sizes, int n_in,
                              void* d_out, int out_size, void* d_ws, size_t ws_size,
                              hipStream_t stream) {
    // workspace: 5 bf16 planes (Qh,Ql,Kh,Kl,Vth) = 5 x 2MB = 10MB
    const size_t NP = (size_t)B_ * S_ * DH;
    unsigned short* Qhp  = (unsigned short*)d_ws;
    unsigned short* Qlp  = Qhp + NP;
    unsigned short* Khp  = Qhp + 2 * NP;
    unsigned short* Klp  = Qhp + 3 * NP;
    unsigned short* Vthp = Qhp + 4 * NP;

    proj_kernel<<<dim3(B_ * S_ / 64, 3), 256, 0, stream>>>(
        d_in[0], d_in[1], d_in[2],   // xq, xk, xv
        d_in[3], d_in[5], d_in[7],   // Wq, Wk, Wv
        d_in[4], d_in[6], d_in[8],   // bq, bk, bv
        Qhp, Qlp, Khp, Klp, Vthp);

    flash_kernel<<<dim3(64, B_), 512, 0, stream>>>(
        Qhp, Qlp, Khp, Klp, Vthp, d_out,
        (const unsigned short*)d_in[0]);
}